// Round 20
// baseline (1930.682 us; speedup 1.0000x reference)
//
#include <hip/hip_runtime.h>

// ---------------------------------------------------------------------------
// QMon (monDEQ) full pipeline, fp32.
//  conv1(8x8,s4)+relu -> conv2(4x4,s2)+relu -> monDEQ PR solver (freq domain)
//  -> border crop -> fc1+relu -> fc2
// Round 20: single fused iteration kernel k_iter (FFT -> matvec(LDS T, L2 V)
//  -> IFFT -> PR, one dispatch/iter; block = one batch's 64 channels;
//  Tf/Yf never leave LDS; last iter folds in final W-pass + crop).
//  Dispatches 103 -> 50. Front-end unchanged from R19.
// ---------------------------------------------------------------------------

#define NB 256
#define NCH 64
#define NP 81
#define NIMG (NB*NCH)
#define MAXIT 50
#define NCAN 41
// canonical set: {ky=0, kx 0..4} U {ky 1..4, kx 0..8}; f = kx*9 + ky
__device__ __host__ inline int CAN2(int l) {
    return (l < 5) ? l*9 : ((l-5)%9)*9 + ((l-5)/9 + 1);
}

// compile-time twiddles: C9[m] = cos(2*pi*m/9), S9[m] = sin(2*pi*m/9)
constexpr float C9[9] = {
  1.0f, 0.76604444311897803f, 0.17364817766693041f, -0.5f,
  -0.93969262078590843f, -0.93969262078590843f, -0.5f,
  0.17364817766693041f, 0.76604444311897803f };
constexpr float S9[9] = {
  0.0f, 0.64278760968653936f, 0.98480775301220802f, 0.86602540378443871f,
  0.34202014332566877f, -0.34202014332566877f, -0.86602540378443871f,
  -0.98480775301220802f, -0.64278760968653936f };

__constant__ float COS9[9] = {
  1.0f, 0.76604444311897803f, 0.17364817766693041f, -0.5f,
  -0.93969262078590843f, -0.93969262078590843f, -0.5f,
  0.17364817766693041f, 0.76604444311897803f };
__constant__ float SIN9[9] = {
  0.0f, 0.64278760968653936f, 0.98480775301220802f, 0.86602540378443871f,
  0.34202014332566877f, -0.34202014332566877f, -0.86602540378443871f,
  -0.98480775301220802f, -0.64278760968653936f };

// ---------------- norm of A_w ----------------------------------------------
__global__ __launch_bounds__(256) void k_norm(const float* __restrict__ Aw,
                                              float* __restrict__ sc) {
    __shared__ float red[256];
    float s = 0.f;
    for (int i = threadIdx.x; i < 64*64*9; i += 256) { float a = Aw[i]; s += a*a; }
    red[threadIdx.x] = s; __syncthreads();
    for (int w = 128; w > 0; w >>= 1) {
        if (threadIdx.x < w) red[threadIdx.x] += red[threadIdx.x + w];
        __syncthreads();
    }
    if (threadIdx.x == 0) { float n = sqrtf(red[0]); sc[0] = n; sc[1] = 1.f/n; }
}

// ---------------- conv1: (256,4,84,84)->(256,32,20,20), k8 s4, relu, x/255 --
__global__ __launch_bounds__(512, 4) void k_conv1(const float* __restrict__ x,
                                                  const float* __restrict__ w,
                                                  const float* __restrict__ bb,
                                                  float* __restrict__ y) {
    __shared__ float xl[7056];
    int blk = blockIdx.x, tid = threadIdx.x;
    int b = blk >> 1, og = (blk & 1) << 4;
    float acc[16];
    #pragma unroll
    for (int o = 0; o < 16; ++o) acc[o] = 0.f;
    int p = tid, oy = p/20, ox = p%20;
    for (int ci = 0; ci < 4; ++ci) {
        __syncthreads();
        const float4* xg = (const float4*)(x + b*28224 + ci*7056);
        for (int i = tid; i < 1764; i += 512) ((float4*)xl)[i] = xg[i];
        __syncthreads();
        if (p < 400) {
            #pragma unroll
            for (int ky = 0; ky < 8; ++ky) {
                const float* xr = xl + (oy*4+ky)*84 + ox*4;
                float4 x0 = *(const float4*)xr;
                float4 x1 = *(const float4*)(xr+4);
                const float* wr = w + og*256 + ci*64 + ky*8;
                #pragma unroll
                for (int o = 0; o < 16; ++o) {
                    const float* wo = wr + o*256;            // uniform -> s_load
                    acc[o] += x0.x*wo[0] + x0.y*wo[1] + x0.z*wo[2] + x0.w*wo[3]
                            + x1.x*wo[4] + x1.y*wo[5] + x1.z*wo[6] + x1.w*wo[7];
                }
            }
        }
    }
    if (p < 400) {
        #pragma unroll
        for (int o = 0; o < 16; ++o)
            y[b*12800 + (og+o)*400 + p] = fmaxf(acc[o]*(1.f/255.f) + bb[og+o], 0.f);
    }
}

// ---------------- conv2: (32,20,20)->(64,9,9) k4 s2 relu -------------------
__global__ __launch_bounds__(512, 2) void k_conv2(const float* __restrict__ h1,
                                                  const float* __restrict__ w2,
                                                  const float* __restrict__ b2,
                                                  float* __restrict__ h2) {
    int blk = blockIdx.x, tid = threadIdx.x;
    int b = blk >> 2, og = (blk & 3) << 4;
    __shared__ float hl[16*400];              // 25,600 B
    __shared__ float wl[16*512];              // 32,768 B
    for (int i = tid; i < 8192; i += 512) wl[i] = w2[og*512 + i];
    float a0[2], a1[2];
    #pragma unroll
    for (int s = 0; s < 2; ++s) { a0[s] = 0.f; a1[s] = 0.f; }
    for (int cp = 0; cp < 2; ++cp) {
        __syncthreads();
        for (int i = tid; i < 6400; i += 512) {
            int ci = i / 400, pix = i % 400, iy = pix / 20, ix = pix % 20;
            hl[ci*400 + ((iy&1)*2 + (ix&1))*100 + (iy>>1)*10 + (ix>>1)]
                = h1[b*12800 + (cp*16 + ci)*400 + pix];
        }
        __syncthreads();
        #pragma unroll
        for (int s = 0; s < 2; ++s) {
            int idx = tid + s*512;
            if (idx < 648) {
                int op = idx/81, p = idx%81;
                int oy = p/9, ox = p%9;
                int toff[16];
                #pragma unroll
                for (int ky = 0; ky < 4; ky++)
                #pragma unroll
                for (int kx = 0; kx < 4; kx++)
                    toff[ky*4+kx] = ((ky&1)*2 + (kx&1))*100
                                  + (oy + (ky>>1))*10 + (ox + (kx>>1));
                const float* w0 = wl + op*2*512 + cp*256;    // 16 ci x 16 taps
                for (int ci = 0; ci < 16; ci++) {
                    float t[16];
                    const float* base = hl + ci*400;
                    #pragma unroll
                    for (int q = 0; q < 16; ++q) t[q] = base[toff[q]];
                    const float* wb0 = w0 + ci*16;
                    const float* wb1 = w0 + 512 + ci*16;
                    #pragma unroll
                    for (int q = 0; q < 16; ++q) {
                        a0[s] += t[q]*wb0[q]; a1[s] += t[q]*wb1[q];
                    }
                }
            }
        }
    }
    #pragma unroll
    for (int s = 0; s < 2; ++s) {
        int idx = tid + s*512;
        if (idx < 648) {
            int op = idx/81, p = idx%81;
            int o = og + op*2;
            h2[b*5184 + o*81 + p]     = fmaxf(a0[s] + b2[o],   0.f);
            h2[b*5184 + (o+1)*81 + p] = fmaxf(a1[s] + b2[o+1], 0.f);
        }
    }
}

// ---------------- bias = circ_conv3x3(h2, U_w) + U_b -> TRANSPOSED [p][img] -
__global__ __launch_bounds__(512, 2) void k_bias(const float* __restrict__ h2,
                                                 const float* __restrict__ Uw,
                                                 const float* __restrict__ Ub,
                                                 float* __restrict__ biasT) {
    int blk = blockIdx.x, tid = threadIdx.x;
    int b = blk >> 2, og = (blk & 3) << 4;
    __shared__ float h2l[5184];               // 20,736 B
    __shared__ float wl[16*576];              // 36,864 B
    __shared__ float bt[1296];                //  5,184 B
    for (int i = tid; i < 5184; i += 512) h2l[i] = h2[b*5184 + i];
    for (int i = tid; i < 9216; i += 512) wl[i] = Uw[og*576 + i];
    __syncthreads();
    for (int idx = tid; idx < 648; idx += 512) {
        int op = idx/81, p = idx%81;
        int i0 = p/9, j0 = p%9;
        int im = (i0+8)%9, ip = (i0+1)%9, jm = (j0+8)%9, jp = (j0+1)%9;
        int toff[9] = { im*9+jm, im*9+j0, im*9+jp,
                        i0*9+jm, i0*9+j0, i0*9+jp,
                        ip*9+jm, ip*9+j0, ip*9+jp };
        float a0 = 0.f, a1 = 0.f;
        const float* w0 = wl + op*2*576;
        for (int ci = 0; ci < 64; ci++) {
            float t[9];
            const float* hb = h2l + ci*81;
            #pragma unroll
            for (int q = 0; q < 9; ++q) t[q] = hb[toff[q]];
            const float* wb0 = w0 + ci*9;
            const float* wb1 = w0 + 576 + ci*9;
            #pragma unroll
            for (int q = 0; q < 9; ++q) { a0 += t[q]*wb0[q]; a1 += t[q]*wb1[q]; }
        }
        bt[(op*2)*81 + p]   = a0 + Ub[og + op*2];
        bt[(op*2+1)*81 + p] = a1 + Ub[og + op*2 + 1];
    }
    __syncthreads();
    for (int idx = tid; idx < 1296; idx += 512) {
        int p2 = idx >> 4, o16 = idx & 15;
        biasT[p2*NIMG + b*64 + og + o16] = bt[o16*81 + p2];
    }
}

// ---------------- Af(f) for canonical f only -------------------------------
__global__ __launch_bounds__(256) void k_af(const float* __restrict__ Aw,
                                            const float* __restrict__ sc,
                                            float2* __restrict__ Af) {
    int l = blockIdx.x; int f = CAN2(l);
    int x = f/9, y = f%9;
    float inv = sc[1];
    for (int pr = threadIdx.x; pr < 4096; pr += 256) {
        const float* a = Aw + pr*9;
        float re = 0.f, im = 0.f;
        #pragma unroll
        for (int dx = 0; dx < 3; dx++)
        #pragma unroll
        for (int dy = 0; dy < 3; dy++) {
            int tt = (x*(dx+8) + y*(dy+8)) % 9;
            float v = a[dx*3+dy] * inv;
            re += v * COS9[tt]; im += v * SIN9[tt];
        }
        Af[f*4096 + pr] = make_float2(re, im);
    }
}

// ---------------- M = 1.1 I + g A^H A ; W^T = (0.9 I - g A^H A)^T ----------
__global__ __launch_bounds__(256) void k_mw(const float2* __restrict__ Af,
                                            const float* __restrict__ gp,
                                            float2* __restrict__ Mmat,
                                            float2* __restrict__ WmT) {
    int l = blockIdx.x >> 2, q = blockIdx.x & 3;
    int f = CAN2(l);
    float g = gp[0];
    __shared__ float2 Al[4096];
    for (int i = threadIdx.x; i < 4096; i += 256) Al[i] = Af[f*4096 + i];
    __syncthreads();
    int e = q*1024 + threadIdx.x;
    #pragma unroll
    for (int rep = 0; rep < 4; ++rep, e += 256) {
        int i = e >> 6, j = e & 63;
        float sr = 0.f, si = 0.f;
        for (int o = 0; o < 64; o++) {
            float2 a = Al[o*64 + i], b = Al[o*64 + j];
            sr += a.x*b.x + a.y*b.y;
            si += a.x*b.y - a.y*b.x;
        }
        Mmat[f*4096 + e] = make_float2((i==j ? 1.1f : 0.f) + g*sr, g*si);
        WmT [f*4096 + j*64 + i] = make_float2((i==j ? 0.9f : 0.f) - g*sr, -g*si);
    }
}

// ---------------- register-resident Gauss-Jordan inverse, 8 waves ----------
__global__ __launch_bounds__(512, 1) void k_inv(float2* __restrict__ Mio) {
    int f = CAN2((int)blockIdx.x);
    __shared__ float2 Mt[64*65];
    __shared__ float2 rowk[2][64];
    __shared__ float2 fcol[2][64];
    int tid = threadIdx.x;
    int i = tid & 63, jg = tid >> 6;            // jg in [0,8)
    float2* Mg = Mio + f*4096;
    for (int e = tid; e < 4096; e += 512) Mt[(e>>6)*65 + (e&63)] = Mg[e];
    __syncthreads();
    float2 r[8];
    #pragma unroll
    for (int jj = 0; jj < 8; ++jj) r[jj] = Mt[i*65 + jg*8 + jj];

    for (int k = 0; k < 64; ++k) {
        int buf = k & 1;
        if (i == k) {
            #pragma unroll
            for (int jj = 0; jj < 8; ++jj) rowk[buf][jg*8 + jj] = r[jj];
        }
        if (jg == (k >> 3)) {
            int sel = k & 7;
            float2 v = r[0];
            #pragma unroll
            for (int jj = 1; jj < 8; ++jj) v = (sel == jj) ? r[jj] : v;
            fcol[buf][i] = v;
        }
        __syncthreads();
        float2 d = rowk[buf][k];
        float den = 1.f / (d.x*d.x + d.y*d.y);
        float pr = d.x*den, pi = -d.y*den;
        float2 fi = fcol[buf][i];
        bool piv = (i == k);
        #pragma unroll
        for (int jj = 0; jj < 8; ++jj) {
            int j = jg*8 + jj;
            float2 rw = rowk[buf][j];
            float2 rkj = (j == k) ? make_float2(pr, pi)
                                  : make_float2(rw.x*pr - rw.y*pi,
                                                rw.x*pi + rw.y*pr);
            if (piv) {
                r[jj] = rkj;
            } else {
                float bx = (j == k) ? 0.f : r[jj].x;
                float by = (j == k) ? 0.f : r[jj].y;
                r[jj] = make_float2(bx - (fi.x*rkj.x - fi.y*rkj.y),
                                    by - (fi.x*rkj.y + fi.y*rkj.x));
            }
        }
    }
    __syncthreads();
    #pragma unroll
    for (int jj = 0; jj < 8; ++jj) Mt[(jg*8 + jj)*65 + i] = r[jj];
    __syncthreads();
    for (int e = tid; e < 4096; e += 512) Mg[e] = Mt[(e>>6)*65 + (e&63)];
}

// ============================================================================
// Fused PR iteration: block = 1 batch (64 channels), 640 thr / 10 waves.
// FFT(u12+bias) -> T(LDS) -> matvec(V from L2) -> Y(LDS) -> IFFT -> PR.
// Last iter: second round with Wm + crop write.
// ============================================================================
__device__ __forceinline__ void fft_st1(const float* tn, float2* bufA,
                                        int lane, int r) {
    #pragma unroll
    for (int ky = 0; ky < 5; ++ky) {
        float sr = 0.f, si = 0.f;
        #pragma unroll
        for (int xx = 0; xx < 9; ++xx) {
            const int m = (ky*xx) % 9;
            sr += tn[xx]*C9[m];
            si -= tn[xx]*S9[m];
        }
        bufA[(r*5 + ky)*64 + lane] = make_float2(sr, si);
    }
}

__device__ __forceinline__ void fft_st2(const float2* bufA, float2* bufT,
                                        int lane, int j) {
    int ky = j >> 1;
    float2 s[9];
    #pragma unroll
    for (int rr = 0; rr < 9; ++rr) s[rr] = bufA[(rr*5 + ky)*64 + lane];
    if ((j & 1) == 0) {
        #pragma unroll
        for (int kx = 0; kx < 5; ++kx) {
            float fr = 0.f, fi = 0.f;
            #pragma unroll
            for (int rr = 0; rr < 9; ++rr) {
                const int m = (kx*rr) % 9;
                fr += s[rr].x*C9[m] + s[rr].y*S9[m];
                fi += s[rr].y*C9[m] - s[rr].x*S9[m];
            }
            int l = (ky == 0) ? kx : 5 + (ky-1)*9 + kx;
            bufT[l*64 + lane] = make_float2(fr, fi);
        }
    } else if (ky > 0) {
        #pragma unroll
        for (int kx = 5; kx < 9; ++kx) {
            float fr = 0.f, fi = 0.f;
            #pragma unroll
            for (int rr = 0; rr < 9; ++rr) {
                const int m = (kx*rr) % 9;
                fr += s[rr].x*C9[m] + s[rr].y*S9[m];
                fi += s[rr].y*C9[m] - s[rr].x*S9[m];
            }
            int l = 5 + (ky-1)*9 + kx;
            bufT[l*64 + lane] = make_float2(fr, fi);
        }
    }
}

__device__ __forceinline__ void mv_phase(const float2* __restrict__ V,
                                         const float2* bufT, float2* bufY,
                                         int lane, int j) {
    for (int l = j; l < NCAN; l += 10) {
        const float2* Vg = V + CAN2(l)*4096 + lane;
        float2 a = make_float2(0.f, 0.f);
        #pragma unroll 8
        for (int c = 0; c < 64; ++c) {
            float2 v = Vg[c*64];
            float2 t = bufT[l*64 + c];           // broadcast
            a.x += v.x*t.x - v.y*t.y;
            a.y += v.x*t.y + v.y*t.x;
        }
        bufY[l*64 + lane] = a;
    }
}

__device__ __forceinline__ void ifft_st1(const float2* bufY, float2* bufW,
                                         int lane, int j) {
    int ky = j >> 1;
    float2 y[9];
    #pragma unroll
    for (int kx = 0; kx < 9; ++kx) {
        int l; bool cj;
        if (ky == 0 && kx >= 5) { l = 9 - kx; cj = true; }
        else { l = (ky == 0) ? kx : 5 + (ky-1)*9 + kx; cj = false; }
        float2 a = bufY[l*64 + lane];
        y[kx] = make_float2(a.x, cj ? -a.y : a.y);
    }
    int r0 = (j & 1) ? 5 : 0, r1 = (j & 1) ? 9 : 5;
    for (int r = r0; r < r1; ++r) {
        float sr = 0.f, si = 0.f;
        #pragma unroll
        for (int kx = 0; kx < 9; ++kx) {
            const int m = (r*kx) % 9;
            sr += y[kx].x*C9[m] - y[kx].y*S9[m];
            si += y[kx].x*S9[m] + y[kx].y*C9[m];
        }
        bufW[(r*5 + ky)*64 + lane] = make_float2(sr, si);
    }
}

__global__ __launch_bounds__(640) void k_iter(float* __restrict__ u12T,
                                              const float* __restrict__ biasT,
                                              const float2* __restrict__ Vm,
                                              const float2* __restrict__ Wm,
                                              float* __restrict__ zc,
                                              int last) {
    __shared__ float2 bufA[2880];
    __shared__ float2 bufB[2880];
    int lane = threadIdx.x & 63, j = threadIdx.x >> 6;   // j in [0,10)
    int gimg = blockIdx.x*64 + lane;
    float u12v[9], bv[9], tn[9];
    // ---- A: tn = u12 + bias; FFT st1 (rows r=j, waves 0-8) ----
    if (j < 9) {
        int r = j;
        #pragma unroll
        for (int xc = 0; xc < 9; ++xc) {
            int gi = (r*9 + xc)*NIMG + gimg;
            u12v[xc] = u12T[gi];
            bv[xc]   = biasT[gi];
            tn[xc]   = u12v[xc] + bv[xc];
        }
        fft_st1(tn, bufA, lane, r);
    }
    __syncthreads();
    fft_st2(bufA, bufB, lane, j);                // bufB = T (canonical)
    __syncthreads();
    mv_phase(Vm, bufB, bufA, lane, j);           // bufA = Y
    __syncthreads();
    ifft_st1(bufA, bufB, lane, j);               // bufB = IFFT st1
    __syncthreads();
    // ---- E: IFFT st2 + PR update (rows r=j, waves 0-8) ----
    if (j < 9) {
        int r = j;
        float2 t1[5];
        #pragma unroll
        for (int ky = 0; ky < 5; ++ky) t1[ky] = bufB[(r*5 + ky)*64 + lane];
        #pragma unroll
        for (int xc = 0; xc < 9; ++xc) {
            float yr = t1[0].x;
            #pragma unroll
            for (int ky = 1; ky < 5; ++ky) {
                const int m = (xc*ky) % 9;
                yr += 2.f*(t1[ky].x*C9[m] - t1[ky].y*S9[m]);
            }
            yr *= (1.f/81.f);
            float un = 2.f*yr - u12v[xc];
            bool interior = (r >= 1 && r <= 7 && xc >= 1 && xc <= 7);
            float zn = interior ? fmaxf(un, 0.f) : 0.f;
            float u12n = 2.f*zn - un;
            u12T[(r*9 + xc)*NIMG + gimg] = u12n;
            tn[xc] = zn;                          // for last-mode FFT(z)
        }
    }
    if (!last) return;
    // ---- last: second round  FFT(z) -> matvec(W) -> IFFT -> crop ----
    __syncthreads();
    if (j < 9) fft_st1(tn, bufA, lane, j);
    __syncthreads();
    fft_st2(bufA, bufB, lane, j);
    __syncthreads();
    mv_phase(Wm, bufB, bufA, lane, j);
    __syncthreads();
    ifft_st1(bufA, bufB, lane, j);
    __syncthreads();
    if (j >= 1 && j <= 7) {
        int r = j;
        float2 t1[5];
        #pragma unroll
        for (int ky = 0; ky < 5; ++ky) t1[ky] = bufB[(r*5 + ky)*64 + lane];
        float* zr = zc + (gimg >> 6)*3136 + (gimg & 63)*49 + (r-1)*7;
        #pragma unroll
        for (int xc = 1; xc < 8; ++xc) {
            float yr = t1[0].x;
            #pragma unroll
            for (int ky = 1; ky < 5; ++ky) {
                const int m = (xc*ky) % 9;
                yr += 2.f*(t1[ky].x*C9[m] - t1[ky].y*S9[m]);
            }
            yr *= (1.f/81.f);
            zr[xc-1] = fmaxf(yr + bv[xc], 0.f);
        }
    }
}

// ---------------- fc1: (256x3136)x(512x3136)^T + b, relu -------------------
__global__ __launch_bounds__(256) void k_fc1(const float* __restrict__ A,
                                             const float* __restrict__ W,
                                             const float* __restrict__ bb,
                                             float* __restrict__ H) {
    int bt = blockIdx.x >> 5, ot = blockIdx.x & 31;
    int b0 = bt*16, o0 = ot*16;
    __shared__ float At[16][65], Bt[16][65];
    int tid = threadIdx.x;
    int row = tid >> 6, col = tid & 63;
    int tb = tid >> 4, to = tid & 15;
    float acc = 0.f;
    for (int k0 = 0; k0 < 3136; k0 += 64) {
        #pragma unroll
        for (int s = 0; s < 4; s++) {
            int rr = row + s*4;
            At[rr][col] = A[(b0+rr)*3136 + k0 + col];
            Bt[rr][col] = W[(o0+rr)*3136 + k0 + col];
        }
        __syncthreads();
        #pragma unroll
        for (int kk = 0; kk < 64; kk++)
            acc += At[tb][kk] * Bt[to][kk];
        __syncthreads();
    }
    H[(b0+tb)*512 + o0+to] = fmaxf(acc + bb[o0+to], 0.f);
}

// ---------------- fc2: (256x512)x(18x512)^T + b ----------------------------
__global__ __launch_bounds__(256) void k_fc2(const float* __restrict__ H,
                                             const float* __restrict__ W,
                                             const float* __restrict__ bb,
                                             float* __restrict__ out) {
    int idx = blockIdx.x*256 + threadIdx.x;
    if (idx >= 4608) return;
    int b = idx/18, o = idx%18;
    const float* h = H + b*512;
    const float* w = W + o*512;
    float acc = 0.f;
    for (int k = 0; k < 512; k++) acc += h[k]*w[k];
    out[idx] = acc + bb[o];
}

// ---------------------------------------------------------------------------
extern "C" void kernel_launch(void* const* d_in, const int* in_sizes, int n_in,
                              void* d_out, int out_size, void* d_ws, size_t ws_size,
                              hipStream_t stream) {
    (void)in_sizes; (void)n_in; (void)out_size; (void)ws_size;
    const float* x   = (const float*)d_in[0];
    const float* c1w = (const float*)d_in[1];
    const float* c1b = (const float*)d_in[2];
    const float* c2w = (const float*)d_in[3];
    const float* c2b = (const float*)d_in[4];
    const float* Uw  = (const float*)d_in[5];
    const float* Ub  = (const float*)d_in[6];
    const float* Aw  = (const float*)d_in[7];
    const float* gp  = (const float*)d_in[8];
    const float* f1w = (const float*)d_in[9];
    const float* f1b = (const float*)d_in[10];
    const float* f2w = (const float*)d_in[11];
    const float* f2b = (const float*)d_in[12];

    float* ws = (float*)d_ws;
    float*  h1    = ws + 0;                      // 3,276,800 f
    float*  biasT = ws + 3276800;                // 1,327,104 f  [p][img]
    float*  u12T  = ws + 4603904;                // 1,327,104 f  [p][img]
    float2* Af    = (float2*)(ws + 5931008);     // 331,776 c2
    float2* Minv  = (float2*)(ws + 6594560);     // 331,776 c2
    float2* WmT   = (float2*)(ws + 7258112);     // 331,776 c2
    float*  zc    = ws + 7921664;                // 802,816 f
    float*  hfc   = ws + 8724480;                // 131,072 f
    float*  sc    = ws + 8855552;                // 2 f
    float*  h2    = ws + 8855556;                // 1,327,104 f

    hipMemsetAsync(u12T, 0, (size_t)1327104*sizeof(float), stream);

    k_norm <<<1,     256, 0, stream>>>(Aw, sc);
    k_conv1<<<512,   512, 0, stream>>>(x, c1w, c1b, h1);
    k_conv2<<<1024,  512, 0, stream>>>(h1, c2w, c2b, h2);
    k_bias <<<1024,  512, 0, stream>>>(h2, Uw, Ub, biasT);
    k_af   <<<NCAN,  256, 0, stream>>>(Aw, sc, Af);
    k_mw   <<<NCAN*4,256, 0, stream>>>(Af, gp, Minv, WmT);
    k_inv  <<<NCAN,  512, 0, stream>>>(Minv);

    for (int it = 0; it < MAXIT; it++)
        k_iter<<<256, 640, 0, stream>>>(u12T, biasT, Minv, WmT, zc,
                                        it == MAXIT-1);

    k_fc1<<<512, 256, 0, stream>>>(zc, f1w, f1b, hfc);
    k_fc2<<<18,  256, 0, stream>>>(hfc, f2w, f2b, (float*)d_out);
}

// Round 21
// 1721.142 us; speedup vs baseline: 1.1217x; 1.1217x over previous
//
#include <hip/hip_runtime.h>

// ---------------------------------------------------------------------------
// QMon (monDEQ) full pipeline, fp32.
//  conv1(8x8,s4)+relu -> conv2(4x4,s2)+relu -> monDEQ PR solver (freq domain)
//  -> border crop -> fc1+relu -> fc2
// Round 21: REVERT to R19 (session best, 1719.8 us). R20's fused k_iter
//  inverted V-amortization (21 -> 343 MB/iter L2 traffic) and regressed.
//  Split k_mv/k_fuse is the correct structure for the FFT<->matvec transpose.
// ---------------------------------------------------------------------------

#define NB 256
#define NCH 64
#define NP 81
#define NIMG (NB*NCH)
#define MAXIT 50
#define NCAN 41
// canonical set: {ky=0, kx 0..4} U {ky 1..4, kx 0..8}; f = kx*9 + ky
__device__ __host__ inline int CAN2(int l) {
    return (l < 5) ? l*9 : ((l-5)%9)*9 + ((l-5)/9 + 1);
}

// compile-time twiddles: C9[m] = cos(2*pi*m/9), S9[m] = sin(2*pi*m/9)
constexpr float C9[9] = {
  1.0f, 0.76604444311897803f, 0.17364817766693041f, -0.5f,
  -0.93969262078590843f, -0.93969262078590843f, -0.5f,
  0.17364817766693041f, 0.76604444311897803f };
constexpr float S9[9] = {
  0.0f, 0.64278760968653936f, 0.98480775301220802f, 0.86602540378443871f,
  0.34202014332566877f, -0.34202014332566877f, -0.86602540378443871f,
  -0.98480775301220802f, -0.64278760968653936f };

__constant__ float COS9[9] = {
  1.0f, 0.76604444311897803f, 0.17364817766693041f, -0.5f,
  -0.93969262078590843f, -0.93969262078590843f, -0.5f,
  0.17364817766693041f, 0.76604444311897803f };
__constant__ float SIN9[9] = {
  0.0f, 0.64278760968653936f, 0.98480775301220802f, 0.86602540378443871f,
  0.34202014332566877f, -0.34202014332566877f, -0.86602540378443871f,
  -0.98480775301220802f, -0.64278760968653936f };

// ---------------- norm of A_w ----------------------------------------------
__global__ __launch_bounds__(256) void k_norm(const float* __restrict__ Aw,
                                              float* __restrict__ sc) {
    __shared__ float red[256];
    float s = 0.f;
    for (int i = threadIdx.x; i < 64*64*9; i += 256) { float a = Aw[i]; s += a*a; }
    red[threadIdx.x] = s; __syncthreads();
    for (int w = 128; w > 0; w >>= 1) {
        if (threadIdx.x < w) red[threadIdx.x] += red[threadIdx.x + w];
        __syncthreads();
    }
    if (threadIdx.x == 0) { float n = sqrtf(red[0]); sc[0] = n; sc[1] = 1.f/n; }
}

// ---------------- conv1: (256,4,84,84)->(256,32,20,20), k8 s4, relu, x/255 --
__global__ __launch_bounds__(512, 4) void k_conv1(const float* __restrict__ x,
                                                  const float* __restrict__ w,
                                                  const float* __restrict__ bb,
                                                  float* __restrict__ y) {
    __shared__ float xl[7056];
    int blk = blockIdx.x, tid = threadIdx.x;
    int b = blk >> 1, og = (blk & 1) << 4;
    float acc[16];
    #pragma unroll
    for (int o = 0; o < 16; ++o) acc[o] = 0.f;
    int p = tid, oy = p/20, ox = p%20;
    for (int ci = 0; ci < 4; ++ci) {
        __syncthreads();
        const float4* xg = (const float4*)(x + b*28224 + ci*7056);
        for (int i = tid; i < 1764; i += 512) ((float4*)xl)[i] = xg[i];
        __syncthreads();
        if (p < 400) {
            #pragma unroll
            for (int ky = 0; ky < 8; ++ky) {
                const float* xr = xl + (oy*4+ky)*84 + ox*4;
                float4 x0 = *(const float4*)xr;
                float4 x1 = *(const float4*)(xr+4);
                const float* wr = w + og*256 + ci*64 + ky*8;
                #pragma unroll
                for (int o = 0; o < 16; ++o) {
                    const float* wo = wr + o*256;            // uniform -> s_load
                    acc[o] += x0.x*wo[0] + x0.y*wo[1] + x0.z*wo[2] + x0.w*wo[3]
                            + x1.x*wo[4] + x1.y*wo[5] + x1.z*wo[6] + x1.w*wo[7];
                }
            }
        }
    }
    if (p < 400) {
        #pragma unroll
        for (int o = 0; o < 16; ++o)
            y[b*12800 + (og+o)*400 + p] = fmaxf(acc[o]*(1.f/255.f) + bb[og+o], 0.f);
    }
}

// ---------------- conv2: (32,20,20)->(64,9,9) k4 s2 relu -------------------
// 4 blocks/image (16 oc); weights in LDS; 2 ci-passes; 512 thr / 8 waves.
__global__ __launch_bounds__(512, 2) void k_conv2(const float* __restrict__ h1,
                                                  const float* __restrict__ w2,
                                                  const float* __restrict__ b2,
                                                  float* __restrict__ h2) {
    int blk = blockIdx.x, tid = threadIdx.x;
    int b = blk >> 2, og = (blk & 3) << 4;
    __shared__ float hl[16*400];              // 25,600 B
    __shared__ float wl[16*512];              // 32,768 B
    for (int i = tid; i < 8192; i += 512) wl[i] = w2[og*512 + i];
    float a0[2], a1[2];
    #pragma unroll
    for (int s = 0; s < 2; ++s) { a0[s] = 0.f; a1[s] = 0.f; }
    for (int cp = 0; cp < 2; ++cp) {
        __syncthreads();
        for (int i = tid; i < 6400; i += 512) {
            int ci = i / 400, pix = i % 400, iy = pix / 20, ix = pix % 20;
            hl[ci*400 + ((iy&1)*2 + (ix&1))*100 + (iy>>1)*10 + (ix>>1)]
                = h1[b*12800 + (cp*16 + ci)*400 + pix];
        }
        __syncthreads();
        #pragma unroll
        for (int s = 0; s < 2; ++s) {
            int idx = tid + s*512;
            if (idx < 648) {
                int op = idx/81, p = idx%81;
                int oy = p/9, ox = p%9;
                int toff[16];
                #pragma unroll
                for (int ky = 0; ky < 4; ky++)
                #pragma unroll
                for (int kx = 0; kx < 4; kx++)
                    toff[ky*4+kx] = ((ky&1)*2 + (kx&1))*100
                                  + (oy + (ky>>1))*10 + (ox + (kx>>1));
                const float* w0 = wl + op*2*512 + cp*256;    // 16 ci x 16 taps
                for (int ci = 0; ci < 16; ci++) {
                    float t[16];
                    const float* base = hl + ci*400;
                    #pragma unroll
                    for (int q = 0; q < 16; ++q) t[q] = base[toff[q]];
                    const float* wb0 = w0 + ci*16;
                    const float* wb1 = w0 + 512 + ci*16;
                    #pragma unroll
                    for (int q = 0; q < 16; ++q) {
                        a0[s] += t[q]*wb0[q]; a1[s] += t[q]*wb1[q];
                    }
                }
            }
        }
    }
    #pragma unroll
    for (int s = 0; s < 2; ++s) {
        int idx = tid + s*512;
        if (idx < 648) {
            int op = idx/81, p = idx%81;
            int o = og + op*2;
            h2[b*5184 + o*81 + p]     = fmaxf(a0[s] + b2[o],   0.f);
            h2[b*5184 + (o+1)*81 + p] = fmaxf(a1[s] + b2[o+1], 0.f);
        }
    }
}

// ---------------- bias = circ_conv3x3(h2, U_w) + U_b -> TRANSPOSED [p][img] -
// 4 blocks/image (16 oc); weights in LDS; 512 thr / 8 waves.
__global__ __launch_bounds__(512, 2) void k_bias(const float* __restrict__ h2,
                                                 const float* __restrict__ Uw,
                                                 const float* __restrict__ Ub,
                                                 float* __restrict__ biasT) {
    int blk = blockIdx.x, tid = threadIdx.x;
    int b = blk >> 2, og = (blk & 3) << 4;
    __shared__ float h2l[5184];               // 20,736 B
    __shared__ float wl[16*576];              // 36,864 B
    __shared__ float bt[1296];                //  5,184 B
    for (int i = tid; i < 5184; i += 512) h2l[i] = h2[b*5184 + i];
    for (int i = tid; i < 9216; i += 512) wl[i] = Uw[og*576 + i];
    __syncthreads();
    for (int idx = tid; idx < 648; idx += 512) {
        int op = idx/81, p = idx%81;
        int i0 = p/9, j0 = p%9;
        int im = (i0+8)%9, ip = (i0+1)%9, jm = (j0+8)%9, jp = (j0+1)%9;
        int toff[9] = { im*9+jm, im*9+j0, im*9+jp,
                        i0*9+jm, i0*9+j0, i0*9+jp,
                        ip*9+jm, ip*9+j0, ip*9+jp };
        float a0 = 0.f, a1 = 0.f;
        const float* w0 = wl + op*2*576;
        for (int ci = 0; ci < 64; ci++) {
            float t[9];
            const float* hb = h2l + ci*81;
            #pragma unroll
            for (int q = 0; q < 9; ++q) t[q] = hb[toff[q]];
            const float* wb0 = w0 + ci*9;
            const float* wb1 = w0 + 576 + ci*9;
            #pragma unroll
            for (int q = 0; q < 9; ++q) { a0 += t[q]*wb0[q]; a1 += t[q]*wb1[q]; }
        }
        bt[(op*2)*81 + p]   = a0 + Ub[og + op*2];
        bt[(op*2+1)*81 + p] = a1 + Ub[og + op*2 + 1];
    }
    __syncthreads();
    for (int idx = tid; idx < 1296; idx += 512) {
        int p2 = idx >> 4, o16 = idx & 15;
        biasT[p2*NIMG + b*64 + og + o16] = bt[o16*81 + p2];
    }
}

// ---------------- Af(f) for canonical f only -------------------------------
__global__ __launch_bounds__(256) void k_af(const float* __restrict__ Aw,
                                            const float* __restrict__ sc,
                                            float2* __restrict__ Af) {
    int l = blockIdx.x; int f = CAN2(l);
    int x = f/9, y = f%9;
    float inv = sc[1];
    for (int pr = threadIdx.x; pr < 4096; pr += 256) {
        const float* a = Aw + pr*9;
        float re = 0.f, im = 0.f;
        #pragma unroll
        for (int dx = 0; dx < 3; dx++)
        #pragma unroll
        for (int dy = 0; dy < 3; dy++) {
            int tt = (x*(dx+8) + y*(dy+8)) % 9;
            float v = a[dx*3+dy] * inv;
            re += v * COS9[tt]; im += v * SIN9[tt];
        }
        Af[f*4096 + pr] = make_float2(re, im);
    }
}

// ---------------- M = 1.1 I + g A^H A ; W^T = (0.9 I - g A^H A)^T ----------
__global__ __launch_bounds__(256) void k_mw(const float2* __restrict__ Af,
                                            const float* __restrict__ gp,
                                            float2* __restrict__ Mmat,
                                            float2* __restrict__ WmT) {
    int l = blockIdx.x >> 2, q = blockIdx.x & 3;
    int f = CAN2(l);
    float g = gp[0];
    __shared__ float2 Al[4096];
    for (int i = threadIdx.x; i < 4096; i += 256) Al[i] = Af[f*4096 + i];
    __syncthreads();
    int e = q*1024 + threadIdx.x;
    #pragma unroll
    for (int rep = 0; rep < 4; ++rep, e += 256) {
        int i = e >> 6, j = e & 63;
        float sr = 0.f, si = 0.f;
        for (int o = 0; o < 64; o++) {
            float2 a = Al[o*64 + i], b = Al[o*64 + j];
            sr += a.x*b.x + a.y*b.y;
            si += a.x*b.y - a.y*b.x;
        }
        Mmat[f*4096 + e] = make_float2((i==j ? 1.1f : 0.f) + g*sr, g*si);
        WmT [f*4096 + j*64 + i] = make_float2((i==j ? 0.9f : 0.f) - g*sr, -g*si);
    }
}

// ---------------- register-resident Gauss-Jordan inverse, 8 waves ----------
__global__ __launch_bounds__(512, 1) void k_inv(float2* __restrict__ Mio) {
    int f = CAN2((int)blockIdx.x);
    __shared__ float2 Mt[64*65];
    __shared__ float2 rowk[2][64];
    __shared__ float2 fcol[2][64];
    int tid = threadIdx.x;
    int i = tid & 63, jg = tid >> 6;            // jg in [0,8)
    float2* Mg = Mio + f*4096;
    for (int e = tid; e < 4096; e += 512) Mt[(e>>6)*65 + (e&63)] = Mg[e];
    __syncthreads();
    float2 r[8];
    #pragma unroll
    for (int jj = 0; jj < 8; ++jj) r[jj] = Mt[i*65 + jg*8 + jj];

    for (int k = 0; k < 64; ++k) {
        int buf = k & 1;
        if (i == k) {
            #pragma unroll
            for (int jj = 0; jj < 8; ++jj) rowk[buf][jg*8 + jj] = r[jj];
        }
        if (jg == (k >> 3)) {
            int sel = k & 7;
            float2 v = r[0];
            #pragma unroll
            for (int jj = 1; jj < 8; ++jj) v = (sel == jj) ? r[jj] : v;
            fcol[buf][i] = v;
        }
        __syncthreads();
        float2 d = rowk[buf][k];
        float den = 1.f / (d.x*d.x + d.y*d.y);
        float pr = d.x*den, pi = -d.y*den;
        float2 fi = fcol[buf][i];
        bool piv = (i == k);
        #pragma unroll
        for (int jj = 0; jj < 8; ++jj) {
            int j = jg*8 + jj;
            float2 rw = rowk[buf][j];
            float2 rkj = (j == k) ? make_float2(pr, pi)
                                  : make_float2(rw.x*pr - rw.y*pi,
                                                rw.x*pi + rw.y*pr);
            if (piv) {
                r[jj] = rkj;
            } else {
                float bx = (j == k) ? 0.f : r[jj].x;
                float by = (j == k) ? 0.f : r[jj].y;
                r[jj] = make_float2(bx - (fi.x*rkj.x - fi.y*rkj.y),
                                    by - (fi.x*rkj.y + fi.y*rkj.x));
            }
        }
    }
    __syncthreads();
    #pragma unroll
    for (int jj = 0; jj < 8; ++jj) Mt[(jg*8 + jj)*65 + i] = r[jj];
    __syncthreads();
    for (int e = tid; e < 4096; e += 512) Mg[e] = Mt[(e>>6)*65 + (e&63)];
}

// ---------------- prologue FFT: Tf = FFT2(biasT), 320 thr / 5 waves --------
__global__ __launch_bounds__(320) void k_fft(const float* __restrict__ biasT,
                                             float2* __restrict__ Tf) {
    __shared__ float2 T1[9*5*64];             // [r][ky<5][img]
    int lane = threadIdx.x & 63, j = threadIdx.x >> 6;   // j in [0,5)
    int gimg = blockIdx.x*64 + lane;
    for (int r = j; r < 9; r += 5) {
        float tn[9];
        #pragma unroll
        for (int xc = 0; xc < 9; ++xc) tn[xc] = biasT[(r*9 + xc)*NIMG + gimg];
        #pragma unroll
        for (int ky = 0; ky < 5; ++ky) {
            float sr = 0.f, si = 0.f;
            #pragma unroll
            for (int xx = 0; xx < 9; ++xx) {
                const int m = (ky*xx) % 9;
                sr += tn[xx]*C9[m];
                si -= tn[xx]*S9[m];
            }
            T1[(r*5 + ky)*64 + lane] = make_float2(sr, si);
        }
    }
    __syncthreads();
    {   // FFT stage 2, column ky = j, canonical freqs
        int ky = j;
        float2 s[9];
        #pragma unroll
        for (int r = 0; r < 9; ++r) s[r] = T1[(r*5 + ky)*64 + lane];
        #pragma unroll
        for (int kx = 0; kx < 9; ++kx) {
            if (kx < 5 || ky > 0) {
                float fr = 0.f, fi = 0.f;
                #pragma unroll
                for (int r = 0; r < 9; ++r) {
                    const int m = (kx*r) % 9;
                    fr += s[r].x*C9[m] + s[r].y*S9[m];
                    fi += s[r].y*C9[m] - s[r].x*S9[m];
                }
                Tf[(kx*9 + ky)*NIMG + gimg] = make_float2(fr, fi);
            }
        }
    }
}

// ---------------- per-frequency matvec, LDS-free, 16 chunks/freq -----------
__global__ __launch_bounds__(256) void k_mv(const float2* __restrict__ Tf,
                                            float2* __restrict__ Yf,
                                            const float2* __restrict__ V) {
    int l = blockIdx.x >> 4, bc = blockIdx.x & 15;   // 41 freqs x 16 chunks
    int f = CAN2(l);
    int lane = threadIdx.x & 63;
    int wid  = __builtin_amdgcn_readfirstlane((int)(threadIdx.x >> 6));
    int b0 = bc*16 + wid*4;
    const float2* Vg = V + f*4096 + lane;
    const float2* Tg = Tf + f*NIMG + b0*64;
    float2 a0 = make_float2(0.f,0.f), a1 = a0, a2 = a0, a3 = a0;
    #pragma unroll 8
    for (int c = 0; c < 64; ++c) {
        float2 v = Vg[c*64];
        float2 t0 = Tg[c], t1 = Tg[64+c], t2 = Tg[128+c], t3 = Tg[192+c];
        a0.x += v.x*t0.x - v.y*t0.y; a0.y += v.x*t0.y + v.y*t0.x;
        a1.x += v.x*t1.x - v.y*t1.y; a1.y += v.x*t1.y + v.y*t1.x;
        a2.x += v.x*t2.x - v.y*t2.y; a2.y += v.x*t2.y + v.y*t2.x;
        a3.x += v.x*t3.x - v.y*t3.y; a3.y += v.x*t3.y + v.y*t3.x;
    }
    float2* Yg = Yf + f*NIMG + b0*64 + lane;
    Yg[0] = a0; Yg[64] = a1; Yg[128] = a2; Yg[192] = a3;
}

// ---------------- fused iteration: IFFT2 + PR + FFT2, 640 thr / 10 waves ---
__global__ __launch_bounds__(640) void k_fuse(const float2* __restrict__ Yf,
                                              float* __restrict__ u12T,
                                              const float* __restrict__ biasT,
                                              float2* __restrict__ Tf,
                                              int last) {
    __shared__ float2 T1[9*5*64];             // [r][ky<5][img]
    int lane = threadIdx.x & 63, j = threadIdx.x >> 6;   // j in [0,10)
    int gimg = blockIdx.x*64 + lane;
    {   // phase 1: load Yf + IFFT st1; column ky = j>>1, rows split by j&1
        int ky = j >> 1;
        float2 y[9];
        #pragma unroll
        for (int kx = 0; kx < 9; ++kx) {
            int fc; bool cj;
            if (ky == 0 && kx >= 5) { fc = (9 - kx)*9; cj = true; }
            else                    { fc = kx*9 + ky;  cj = false; }
            float2 a = Yf[fc*NIMG + gimg];
            y[kx] = make_float2(a.x, cj ? -a.y : a.y);
        }
        if ((j & 1) == 0) {
            #pragma unroll
            for (int r = 0; r < 5; ++r) {
                float sr = 0.f, si = 0.f;
                #pragma unroll
                for (int kx = 0; kx < 9; ++kx) {
                    const int m = (r*kx) % 9;
                    sr += y[kx].x*C9[m] - y[kx].y*S9[m];
                    si += y[kx].x*S9[m] + y[kx].y*C9[m];
                }
                T1[(r*5 + ky)*64 + lane] = make_float2(sr, si);
            }
        } else {
            #pragma unroll
            for (int r = 5; r < 9; ++r) {
                float sr = 0.f, si = 0.f;
                #pragma unroll
                for (int kx = 0; kx < 9; ++kx) {
                    const int m = (r*kx) % 9;
                    sr += y[kx].x*C9[m] - y[kx].y*S9[m];
                    si += y[kx].x*S9[m] + y[kx].y*C9[m];
                }
                T1[(r*5 + ky)*64 + lane] = make_float2(sr, si);
            }
        }
    }
    __syncthreads();
    if (j < 9) {   // phase 2: IFFT st2 (doubled-real) + PR + FFT st1, row r=j
        int r = j;
        float2 t1[5];
        #pragma unroll
        for (int ky = 0; ky < 5; ++ky) t1[ky] = T1[(r*5 + ky)*64 + lane];
        float tn[9];
        #pragma unroll
        for (int xc = 0; xc < 9; ++xc) {
            float yr = t1[0].x;
            #pragma unroll
            for (int ky = 1; ky < 5; ++ky) {
                const int m = (xc*ky) % 9;
                yr += 2.f*(t1[ky].x*C9[m] - t1[ky].y*S9[m]);
            }
            yr *= (1.f/81.f);
            int gi = (r*9 + xc)*NIMG + gimg;
            float u12v = u12T[gi];
            float un = 2.f*yr - u12v;
            bool interior = (r >= 1 && r <= 7 && xc >= 1 && xc <= 7);
            float zn = interior ? fmaxf(un, 0.f) : 0.f;
            float u12n = 2.f*zn - un;
            u12T[gi] = u12n;
            tn[xc] = last ? zn : (u12n + biasT[gi]);
        }
        #pragma unroll
        for (int ky = 0; ky < 5; ++ky) {
            float sr = 0.f, si = 0.f;
            #pragma unroll
            for (int xx = 0; xx < 9; ++xx) {
                const int m = (ky*xx) % 9;
                sr += tn[xx]*C9[m];
                si -= tn[xx]*S9[m];
            }
            T1[(r*5 + ky)*64 + lane] = make_float2(sr, si);
        }
    }
    __syncthreads();
    {   // phase 3: FFT st2; column ky = j>>1, kx split by j&1
        int ky = j >> 1;
        float2 s[9];
        #pragma unroll
        for (int rr = 0; rr < 9; ++rr) s[rr] = T1[(rr*5 + ky)*64 + lane];
        if ((j & 1) == 0) {
            #pragma unroll
            for (int kx = 0; kx < 5; ++kx) {
                float fr = 0.f, fi = 0.f;
                #pragma unroll
                for (int rr = 0; rr < 9; ++rr) {
                    const int m = (kx*rr) % 9;
                    fr += s[rr].x*C9[m] + s[rr].y*S9[m];
                    fi += s[rr].y*C9[m] - s[rr].x*S9[m];
                }
                Tf[(kx*9 + ky)*NIMG + gimg] = make_float2(fr, fi);
            }
        } else if (ky > 0) {
            #pragma unroll
            for (int kx = 5; kx < 9; ++kx) {
                float fr = 0.f, fi = 0.f;
                #pragma unroll
                for (int rr = 0; rr < 9; ++rr) {
                    const int m = (kx*rr) % 9;
                    fr += s[rr].x*C9[m] + s[rr].y*S9[m];
                    fi += s[rr].y*C9[m] - s[rr].x*S9[m];
                }
                Tf[(kx*9 + ky)*NIMG + gimg] = make_float2(fr, fi);
            }
        }
    }
}

// ---------------- final: IFFT(W z) -> relu(+bias) -> crop, 320 thr ---------
__global__ __launch_bounds__(320) void k_crop(const float2* __restrict__ Yf,
                                              const float* __restrict__ biasT,
                                              float* __restrict__ zc) {
    __shared__ float2 T1[9*5*64];
    int lane = threadIdx.x & 63, j = threadIdx.x >> 6;
    int gimg = blockIdx.x*64 + lane;
    {   // mirror-load + IFFT st1, column ky = j
        int ky = j;
        float2 y[9];
        #pragma unroll
        for (int kx = 0; kx < 9; ++kx) {
            int fc; bool cj;
            if (ky == 0 && kx >= 5) { fc = (9 - kx)*9; cj = true; }
            else                    { fc = kx*9 + ky;  cj = false; }
            float2 a = Yf[fc*NIMG + gimg];
            y[kx] = make_float2(a.x, cj ? -a.y : a.y);
        }
        #pragma unroll
        for (int r = 0; r < 9; ++r) {
            float sr = 0.f, si = 0.f;
            #pragma unroll
            for (int kx = 0; kx < 9; ++kx) {
                const int m = (r*kx) % 9;
                sr += y[kx].x*C9[m] - y[kx].y*S9[m];
                si += y[kx].x*S9[m] + y[kx].y*C9[m];
            }
            T1[(r*5 + ky)*64 + lane] = make_float2(sr, si);
        }
    }
    __syncthreads();
    for (int r = 1 + j; r <= 7; r += 5) {
        float2 t1[5];
        #pragma unroll
        for (int ky = 0; ky < 5; ++ky) t1[ky] = T1[(r*5 + ky)*64 + lane];
        float* zr = zc + (gimg >> 6)*3136 + (gimg & 63)*49 + (r-1)*7;
        #pragma unroll
        for (int xc = 1; xc < 8; ++xc) {
            float yr = t1[0].x;
            #pragma unroll
            for (int ky = 1; ky < 5; ++ky) {
                const int m = (xc*ky) % 9;
                yr += 2.f*(t1[ky].x*C9[m] - t1[ky].y*S9[m]);
            }
            yr *= (1.f/81.f);
            zr[xc-1] = fmaxf(yr + biasT[(r*9 + xc)*NIMG + gimg], 0.f);
        }
    }
}

// ---------------- fc1: (256x3136)x(512x3136)^T + b, relu -------------------
__global__ __launch_bounds__(256) void k_fc1(const float* __restrict__ A,
                                             const float* __restrict__ W,
                                             const float* __restrict__ bb,
                                             float* __restrict__ H) {
    int bt = blockIdx.x >> 5, ot = blockIdx.x & 31;
    int b0 = bt*16, o0 = ot*16;
    __shared__ float At[16][65], Bt[16][65];
    int tid = threadIdx.x;
    int row = tid >> 6, col = tid & 63;
    int tb = tid >> 4, to = tid & 15;
    float acc = 0.f;
    for (int k0 = 0; k0 < 3136; k0 += 64) {
        #pragma unroll
        for (int s = 0; s < 4; s++) {
            int rr = row + s*4;
            At[rr][col] = A[(b0+rr)*3136 + k0 + col];
            Bt[rr][col] = W[(o0+rr)*3136 + k0 + col];
        }
        __syncthreads();
        #pragma unroll
        for (int kk = 0; kk < 64; kk++)
            acc += At[tb][kk] * Bt[to][kk];
        __syncthreads();
    }
    H[(b0+tb)*512 + o0+to] = fmaxf(acc + bb[o0+to], 0.f);
}

// ---------------- fc2: (256x512)x(18x512)^T + b ----------------------------
__global__ __launch_bounds__(256) void k_fc2(const float* __restrict__ H,
                                             const float* __restrict__ W,
                                             const float* __restrict__ bb,
                                             float* __restrict__ out) {
    int idx = blockIdx.x*256 + threadIdx.x;
    if (idx >= 4608) return;
    int b = idx/18, o = idx%18;
    const float* h = H + b*512;
    const float* w = W + o*512;
    float acc = 0.f;
    for (int k = 0; k < 512; k++) acc += h[k]*w[k];
    out[idx] = acc + bb[o];
}

// ---------------------------------------------------------------------------
extern "C" void kernel_launch(void* const* d_in, const int* in_sizes, int n_in,
                              void* d_out, int out_size, void* d_ws, size_t ws_size,
                              hipStream_t stream) {
    (void)in_sizes; (void)n_in; (void)out_size; (void)ws_size;
    const float* x   = (const float*)d_in[0];
    const float* c1w = (const float*)d_in[1];
    const float* c1b = (const float*)d_in[2];
    const float* c2w = (const float*)d_in[3];
    const float* c2b = (const float*)d_in[4];
    const float* Uw  = (const float*)d_in[5];
    const float* Ub  = (const float*)d_in[6];
    const float* Aw  = (const float*)d_in[7];
    const float* gp  = (const float*)d_in[8];
    const float* f1w = (const float*)d_in[9];
    const float* f1b = (const float*)d_in[10];
    const float* f2w = (const float*)d_in[11];
    const float* f2b = (const float*)d_in[12];

    float* ws = (float*)d_ws;
    float*  h1    = ws + 0;                      // 3,276,800 f
    float2* Tf    = (float2*)(ws + 0);           // alias h1 (dead after conv2)
    float*  biasT = ws + 3276800;                // 1,327,104 f  [p][img]
    float*  u12T  = ws + 4603904;                // 1,327,104 f  [p][img]
    float2* Yf    = (float2*)(ws + 5931008);     // 1,327,104 c2
    float2* Af    = (float2*)(ws + 8585216);     // 331,776 c2
    float2* Minv  = (float2*)(ws + 9248768);     // 331,776 c2
    float2* WmT   = (float2*)(ws + 9912320);     // 331,776 c2
    float*  zc    = ws + 10575872;               // 802,816 f
    float*  hfc   = ws + 11378688;               // 131,072 f
    float*  sc    = ws + 11509760;               // 2 f
    float*  h2    = ws + 11509764;               // 1,327,104 f

    hipMemsetAsync(u12T, 0, (size_t)1327104*sizeof(float), stream);

    k_norm <<<1,     256, 0, stream>>>(Aw, sc);
    k_conv1<<<512,   512, 0, stream>>>(x, c1w, c1b, h1);
    k_conv2<<<1024,  512, 0, stream>>>(h1, c2w, c2b, h2);
    k_bias <<<1024,  512, 0, stream>>>(h2, Uw, Ub, biasT);
    k_af   <<<NCAN,  256, 0, stream>>>(Aw, sc, Af);
    k_mw   <<<NCAN*4,256, 0, stream>>>(Af, gp, Minv, WmT);
    k_inv  <<<NCAN,  512, 0, stream>>>(Minv);

    // iteration 0 forward: u12 = 0, so T = FFT(bias)
    k_fft<<<256, 320, 0, stream>>>(biasT, Tf);
    for (int it = 0; it < MAXIT; it++) {
        k_mv  <<<NCAN*16, 256, 0, stream>>>(Tf, Yf, Minv);
        k_fuse<<<256,     640, 0, stream>>>(Yf, u12T, biasT, Tf, it == MAXIT-1);
    }
    // final pass: brelu(W z + bias) -> crop  (Tf already = FFT(z))
    k_mv  <<<NCAN*16, 256, 0, stream>>>(Tf, Yf, WmT);
    k_crop<<<256,     320, 0, stream>>>(Yf, biasT, zc);

    k_fc1<<<512, 256, 0, stream>>>(zc, f1w, f1b, hfc);
    k_fc2<<<18,  256, 0, stream>>>(hfc, f2w, f2b, (float*)d_out);
}

// Round 22
// 1715.124 us; speedup vs baseline: 1.1257x; 1.0035x over previous
//
#include <hip/hip_runtime.h>

// ---------------------------------------------------------------------------
// QMon (monDEQ) full pipeline, fp32.
//  conv1(8x8,s4)+relu -> conv2(4x4,s2)+relu -> monDEQ PR solver (freq domain)
//  -> border crop -> fc1+relu -> fc2
// Round 22: R19 frozen + k_fc1 inner loop vectorized (float4 LDS reads over
//  kk: 2x ds_read_b128 per 4 FMA vs 8x ds_read_b32 -> 4x fewer LDS insts).
// ---------------------------------------------------------------------------

#define NB 256
#define NCH 64
#define NP 81
#define NIMG (NB*NCH)
#define MAXIT 50
#define NCAN 41
// canonical set: {ky=0, kx 0..4} U {ky 1..4, kx 0..8}; f = kx*9 + ky
__device__ __host__ inline int CAN2(int l) {
    return (l < 5) ? l*9 : ((l-5)%9)*9 + ((l-5)/9 + 1);
}

// compile-time twiddles: C9[m] = cos(2*pi*m/9), S9[m] = sin(2*pi*m/9)
constexpr float C9[9] = {
  1.0f, 0.76604444311897803f, 0.17364817766693041f, -0.5f,
  -0.93969262078590843f, -0.93969262078590843f, -0.5f,
  0.17364817766693041f, 0.76604444311897803f };
constexpr float S9[9] = {
  0.0f, 0.64278760968653936f, 0.98480775301220802f, 0.86602540378443871f,
  0.34202014332566877f, -0.34202014332566877f, -0.86602540378443871f,
  -0.98480775301220802f, -0.64278760968653936f };

__constant__ float COS9[9] = {
  1.0f, 0.76604444311897803f, 0.17364817766693041f, -0.5f,
  -0.93969262078590843f, -0.93969262078590843f, -0.5f,
  0.17364817766693041f, 0.76604444311897803f };
__constant__ float SIN9[9] = {
  0.0f, 0.64278760968653936f, 0.98480775301220802f, 0.86602540378443871f,
  0.34202014332566877f, -0.34202014332566877f, -0.86602540378443871f,
  -0.98480775301220802f, -0.64278760968653936f };

// ---------------- norm of A_w ----------------------------------------------
__global__ __launch_bounds__(256) void k_norm(const float* __restrict__ Aw,
                                              float* __restrict__ sc) {
    __shared__ float red[256];
    float s = 0.f;
    for (int i = threadIdx.x; i < 64*64*9; i += 256) { float a = Aw[i]; s += a*a; }
    red[threadIdx.x] = s; __syncthreads();
    for (int w = 128; w > 0; w >>= 1) {
        if (threadIdx.x < w) red[threadIdx.x] += red[threadIdx.x + w];
        __syncthreads();
    }
    if (threadIdx.x == 0) { float n = sqrtf(red[0]); sc[0] = n; sc[1] = 1.f/n; }
}

// ---------------- conv1: (256,4,84,84)->(256,32,20,20), k8 s4, relu, x/255 --
__global__ __launch_bounds__(512, 4) void k_conv1(const float* __restrict__ x,
                                                  const float* __restrict__ w,
                                                  const float* __restrict__ bb,
                                                  float* __restrict__ y) {
    __shared__ float xl[7056];
    int blk = blockIdx.x, tid = threadIdx.x;
    int b = blk >> 1, og = (blk & 1) << 4;
    float acc[16];
    #pragma unroll
    for (int o = 0; o < 16; ++o) acc[o] = 0.f;
    int p = tid, oy = p/20, ox = p%20;
    for (int ci = 0; ci < 4; ++ci) {
        __syncthreads();
        const float4* xg = (const float4*)(x + b*28224 + ci*7056);
        for (int i = tid; i < 1764; i += 512) ((float4*)xl)[i] = xg[i];
        __syncthreads();
        if (p < 400) {
            #pragma unroll
            for (int ky = 0; ky < 8; ++ky) {
                const float* xr = xl + (oy*4+ky)*84 + ox*4;
                float4 x0 = *(const float4*)xr;
                float4 x1 = *(const float4*)(xr+4);
                const float* wr = w + og*256 + ci*64 + ky*8;
                #pragma unroll
                for (int o = 0; o < 16; ++o) {
                    const float* wo = wr + o*256;            // uniform -> s_load
                    acc[o] += x0.x*wo[0] + x0.y*wo[1] + x0.z*wo[2] + x0.w*wo[3]
                            + x1.x*wo[4] + x1.y*wo[5] + x1.z*wo[6] + x1.w*wo[7];
                }
            }
        }
    }
    if (p < 400) {
        #pragma unroll
        for (int o = 0; o < 16; ++o)
            y[b*12800 + (og+o)*400 + p] = fmaxf(acc[o]*(1.f/255.f) + bb[og+o], 0.f);
    }
}

// ---------------- conv2: (32,20,20)->(64,9,9) k4 s2 relu -------------------
__global__ __launch_bounds__(512, 2) void k_conv2(const float* __restrict__ h1,
                                                  const float* __restrict__ w2,
                                                  const float* __restrict__ b2,
                                                  float* __restrict__ h2) {
    int blk = blockIdx.x, tid = threadIdx.x;
    int b = blk >> 2, og = (blk & 3) << 4;
    __shared__ float hl[16*400];              // 25,600 B
    __shared__ float wl[16*512];              // 32,768 B
    for (int i = tid; i < 8192; i += 512) wl[i] = w2[og*512 + i];
    float a0[2], a1[2];
    #pragma unroll
    for (int s = 0; s < 2; ++s) { a0[s] = 0.f; a1[s] = 0.f; }
    for (int cp = 0; cp < 2; ++cp) {
        __syncthreads();
        for (int i = tid; i < 6400; i += 512) {
            int ci = i / 400, pix = i % 400, iy = pix / 20, ix = pix % 20;
            hl[ci*400 + ((iy&1)*2 + (ix&1))*100 + (iy>>1)*10 + (ix>>1)]
                = h1[b*12800 + (cp*16 + ci)*400 + pix];
        }
        __syncthreads();
        #pragma unroll
        for (int s = 0; s < 2; ++s) {
            int idx = tid + s*512;
            if (idx < 648) {
                int op = idx/81, p = idx%81;
                int oy = p/9, ox = p%9;
                int toff[16];
                #pragma unroll
                for (int ky = 0; ky < 4; ky++)
                #pragma unroll
                for (int kx = 0; kx < 4; kx++)
                    toff[ky*4+kx] = ((ky&1)*2 + (kx&1))*100
                                  + (oy + (ky>>1))*10 + (ox + (kx>>1));
                const float* w0 = wl + op*2*512 + cp*256;    // 16 ci x 16 taps
                for (int ci = 0; ci < 16; ci++) {
                    float t[16];
                    const float* base = hl + ci*400;
                    #pragma unroll
                    for (int q = 0; q < 16; ++q) t[q] = base[toff[q]];
                    const float* wb0 = w0 + ci*16;
                    const float* wb1 = w0 + 512 + ci*16;
                    #pragma unroll
                    for (int q = 0; q < 16; ++q) {
                        a0[s] += t[q]*wb0[q]; a1[s] += t[q]*wb1[q];
                    }
                }
            }
        }
    }
    #pragma unroll
    for (int s = 0; s < 2; ++s) {
        int idx = tid + s*512;
        if (idx < 648) {
            int op = idx/81, p = idx%81;
            int o = og + op*2;
            h2[b*5184 + o*81 + p]     = fmaxf(a0[s] + b2[o],   0.f);
            h2[b*5184 + (o+1)*81 + p] = fmaxf(a1[s] + b2[o+1], 0.f);
        }
    }
}

// ---------------- bias = circ_conv3x3(h2, U_w) + U_b -> TRANSPOSED [p][img] -
__global__ __launch_bounds__(512, 2) void k_bias(const float* __restrict__ h2,
                                                 const float* __restrict__ Uw,
                                                 const float* __restrict__ Ub,
                                                 float* __restrict__ biasT) {
    int blk = blockIdx.x, tid = threadIdx.x;
    int b = blk >> 2, og = (blk & 3) << 4;
    __shared__ float h2l[5184];               // 20,736 B
    __shared__ float wl[16*576];              // 36,864 B
    __shared__ float bt[1296];                //  5,184 B
    for (int i = tid; i < 5184; i += 512) h2l[i] = h2[b*5184 + i];
    for (int i = tid; i < 9216; i += 512) wl[i] = Uw[og*576 + i];
    __syncthreads();
    for (int idx = tid; idx < 648; idx += 512) {
        int op = idx/81, p = idx%81;
        int i0 = p/9, j0 = p%9;
        int im = (i0+8)%9, ip = (i0+1)%9, jm = (j0+8)%9, jp = (j0+1)%9;
        int toff[9] = { im*9+jm, im*9+j0, im*9+jp,
                        i0*9+jm, i0*9+j0, i0*9+jp,
                        ip*9+jm, ip*9+j0, ip*9+jp };
        float a0 = 0.f, a1 = 0.f;
        const float* w0 = wl + op*2*576;
        for (int ci = 0; ci < 64; ci++) {
            float t[9];
            const float* hb = h2l + ci*81;
            #pragma unroll
            for (int q = 0; q < 9; ++q) t[q] = hb[toff[q]];
            const float* wb0 = w0 + ci*9;
            const float* wb1 = w0 + 576 + ci*9;
            #pragma unroll
            for (int q = 0; q < 9; ++q) { a0 += t[q]*wb0[q]; a1 += t[q]*wb1[q]; }
        }
        bt[(op*2)*81 + p]   = a0 + Ub[og + op*2];
        bt[(op*2+1)*81 + p] = a1 + Ub[og + op*2 + 1];
    }
    __syncthreads();
    for (int idx = tid; idx < 1296; idx += 512) {
        int p2 = idx >> 4, o16 = idx & 15;
        biasT[p2*NIMG + b*64 + og + o16] = bt[o16*81 + p2];
    }
}

// ---------------- Af(f) for canonical f only -------------------------------
__global__ __launch_bounds__(256) void k_af(const float* __restrict__ Aw,
                                            const float* __restrict__ sc,
                                            float2* __restrict__ Af) {
    int l = blockIdx.x; int f = CAN2(l);
    int x = f/9, y = f%9;
    float inv = sc[1];
    for (int pr = threadIdx.x; pr < 4096; pr += 256) {
        const float* a = Aw + pr*9;
        float re = 0.f, im = 0.f;
        #pragma unroll
        for (int dx = 0; dx < 3; dx++)
        #pragma unroll
        for (int dy = 0; dy < 3; dy++) {
            int tt = (x*(dx+8) + y*(dy+8)) % 9;
            float v = a[dx*3+dy] * inv;
            re += v * COS9[tt]; im += v * SIN9[tt];
        }
        Af[f*4096 + pr] = make_float2(re, im);
    }
}

// ---------------- M = 1.1 I + g A^H A ; W^T = (0.9 I - g A^H A)^T ----------
__global__ __launch_bounds__(256) void k_mw(const float2* __restrict__ Af,
                                            const float* __restrict__ gp,
                                            float2* __restrict__ Mmat,
                                            float2* __restrict__ WmT) {
    int l = blockIdx.x >> 2, q = blockIdx.x & 3;
    int f = CAN2(l);
    float g = gp[0];
    __shared__ float2 Al[4096];
    for (int i = threadIdx.x; i < 4096; i += 256) Al[i] = Af[f*4096 + i];
    __syncthreads();
    int e = q*1024 + threadIdx.x;
    #pragma unroll
    for (int rep = 0; rep < 4; ++rep, e += 256) {
        int i = e >> 6, j = e & 63;
        float sr = 0.f, si = 0.f;
        for (int o = 0; o < 64; o++) {
            float2 a = Al[o*64 + i], b = Al[o*64 + j];
            sr += a.x*b.x + a.y*b.y;
            si += a.x*b.y - a.y*b.x;
        }
        Mmat[f*4096 + e] = make_float2((i==j ? 1.1f : 0.f) + g*sr, g*si);
        WmT [f*4096 + j*64 + i] = make_float2((i==j ? 0.9f : 0.f) - g*sr, -g*si);
    }
}

// ---------------- register-resident Gauss-Jordan inverse, 8 waves ----------
__global__ __launch_bounds__(512, 1) void k_inv(float2* __restrict__ Mio) {
    int f = CAN2((int)blockIdx.x);
    __shared__ float2 Mt[64*65];
    __shared__ float2 rowk[2][64];
    __shared__ float2 fcol[2][64];
    int tid = threadIdx.x;
    int i = tid & 63, jg = tid >> 6;            // jg in [0,8)
    float2* Mg = Mio + f*4096;
    for (int e = tid; e < 4096; e += 512) Mt[(e>>6)*65 + (e&63)] = Mg[e];
    __syncthreads();
    float2 r[8];
    #pragma unroll
    for (int jj = 0; jj < 8; ++jj) r[jj] = Mt[i*65 + jg*8 + jj];

    for (int k = 0; k < 64; ++k) {
        int buf = k & 1;
        if (i == k) {
            #pragma unroll
            for (int jj = 0; jj < 8; ++jj) rowk[buf][jg*8 + jj] = r[jj];
        }
        if (jg == (k >> 3)) {
            int sel = k & 7;
            float2 v = r[0];
            #pragma unroll
            for (int jj = 1; jj < 8; ++jj) v = (sel == jj) ? r[jj] : v;
            fcol[buf][i] = v;
        }
        __syncthreads();
        float2 d = rowk[buf][k];
        float den = 1.f / (d.x*d.x + d.y*d.y);
        float pr = d.x*den, pi = -d.y*den;
        float2 fi = fcol[buf][i];
        bool piv = (i == k);
        #pragma unroll
        for (int jj = 0; jj < 8; ++jj) {
            int j = jg*8 + jj;
            float2 rw = rowk[buf][j];
            float2 rkj = (j == k) ? make_float2(pr, pi)
                                  : make_float2(rw.x*pr - rw.y*pi,
                                                rw.x*pi + rw.y*pr);
            if (piv) {
                r[jj] = rkj;
            } else {
                float bx = (j == k) ? 0.f : r[jj].x;
                float by = (j == k) ? 0.f : r[jj].y;
                r[jj] = make_float2(bx - (fi.x*rkj.x - fi.y*rkj.y),
                                    by - (fi.x*rkj.y + fi.y*rkj.x));
            }
        }
    }
    __syncthreads();
    #pragma unroll
    for (int jj = 0; jj < 8; ++jj) Mt[(jg*8 + jj)*65 + i] = r[jj];
    __syncthreads();
    for (int e = tid; e < 4096; e += 512) Mg[e] = Mt[(e>>6)*65 + (e&63)];
}

// ---------------- prologue FFT: Tf = FFT2(biasT), 320 thr / 5 waves --------
__global__ __launch_bounds__(320) void k_fft(const float* __restrict__ biasT,
                                             float2* __restrict__ Tf) {
    __shared__ float2 T1[9*5*64];             // [r][ky<5][img]
    int lane = threadIdx.x & 63, j = threadIdx.x >> 6;   // j in [0,5)
    int gimg = blockIdx.x*64 + lane;
    for (int r = j; r < 9; r += 5) {
        float tn[9];
        #pragma unroll
        for (int xc = 0; xc < 9; ++xc) tn[xc] = biasT[(r*9 + xc)*NIMG + gimg];
        #pragma unroll
        for (int ky = 0; ky < 5; ++ky) {
            float sr = 0.f, si = 0.f;
            #pragma unroll
            for (int xx = 0; xx < 9; ++xx) {
                const int m = (ky*xx) % 9;
                sr += tn[xx]*C9[m];
                si -= tn[xx]*S9[m];
            }
            T1[(r*5 + ky)*64 + lane] = make_float2(sr, si);
        }
    }
    __syncthreads();
    {   // FFT stage 2, column ky = j, canonical freqs
        int ky = j;
        float2 s[9];
        #pragma unroll
        for (int r = 0; r < 9; ++r) s[r] = T1[(r*5 + ky)*64 + lane];
        #pragma unroll
        for (int kx = 0; kx < 9; ++kx) {
            if (kx < 5 || ky > 0) {
                float fr = 0.f, fi = 0.f;
                #pragma unroll
                for (int r = 0; r < 9; ++r) {
                    const int m = (kx*r) % 9;
                    fr += s[r].x*C9[m] + s[r].y*S9[m];
                    fi += s[r].y*C9[m] - s[r].x*S9[m];
                }
                Tf[(kx*9 + ky)*NIMG + gimg] = make_float2(fr, fi);
            }
        }
    }
}

// ---------------- per-frequency matvec, LDS-free, 16 chunks/freq -----------
__global__ __launch_bounds__(256) void k_mv(const float2* __restrict__ Tf,
                                            float2* __restrict__ Yf,
                                            const float2* __restrict__ V) {
    int l = blockIdx.x >> 4, bc = blockIdx.x & 15;   // 41 freqs x 16 chunks
    int f = CAN2(l);
    int lane = threadIdx.x & 63;
    int wid  = __builtin_amdgcn_readfirstlane((int)(threadIdx.x >> 6));
    int b0 = bc*16 + wid*4;
    const float2* Vg = V + f*4096 + lane;
    const float2* Tg = Tf + f*NIMG + b0*64;
    float2 a0 = make_float2(0.f,0.f), a1 = a0, a2 = a0, a3 = a0;
    #pragma unroll 8
    for (int c = 0; c < 64; ++c) {
        float2 v = Vg[c*64];
        float2 t0 = Tg[c], t1 = Tg[64+c], t2 = Tg[128+c], t3 = Tg[192+c];
        a0.x += v.x*t0.x - v.y*t0.y; a0.y += v.x*t0.y + v.y*t0.x;
        a1.x += v.x*t1.x - v.y*t1.y; a1.y += v.x*t1.y + v.y*t1.x;
        a2.x += v.x*t2.x - v.y*t2.y; a2.y += v.x*t2.y + v.y*t2.x;
        a3.x += v.x*t3.x - v.y*t3.y; a3.y += v.x*t3.y + v.y*t3.x;
    }
    float2* Yg = Yf + f*NIMG + b0*64 + lane;
    Yg[0] = a0; Yg[64] = a1; Yg[128] = a2; Yg[192] = a3;
}

// ---------------- fused iteration: IFFT2 + PR + FFT2, 640 thr / 10 waves ---
__global__ __launch_bounds__(640) void k_fuse(const float2* __restrict__ Yf,
                                              float* __restrict__ u12T,
                                              const float* __restrict__ biasT,
                                              float2* __restrict__ Tf,
                                              int last) {
    __shared__ float2 T1[9*5*64];             // [r][ky<5][img]
    int lane = threadIdx.x & 63, j = threadIdx.x >> 6;   // j in [0,10)
    int gimg = blockIdx.x*64 + lane;
    {   // phase 1: load Yf + IFFT st1; column ky = j>>1, rows split by j&1
        int ky = j >> 1;
        float2 y[9];
        #pragma unroll
        for (int kx = 0; kx < 9; ++kx) {
            int fc; bool cj;
            if (ky == 0 && kx >= 5) { fc = (9 - kx)*9; cj = true; }
            else                    { fc = kx*9 + ky;  cj = false; }
            float2 a = Yf[fc*NIMG + gimg];
            y[kx] = make_float2(a.x, cj ? -a.y : a.y);
        }
        if ((j & 1) == 0) {
            #pragma unroll
            for (int r = 0; r < 5; ++r) {
                float sr = 0.f, si = 0.f;
                #pragma unroll
                for (int kx = 0; kx < 9; ++kx) {
                    const int m = (r*kx) % 9;
                    sr += y[kx].x*C9[m] - y[kx].y*S9[m];
                    si += y[kx].x*S9[m] + y[kx].y*C9[m];
                }
                T1[(r*5 + ky)*64 + lane] = make_float2(sr, si);
            }
        } else {
            #pragma unroll
            for (int r = 5; r < 9; ++r) {
                float sr = 0.f, si = 0.f;
                #pragma unroll
                for (int kx = 0; kx < 9; ++kx) {
                    const int m = (r*kx) % 9;
                    sr += y[kx].x*C9[m] - y[kx].y*S9[m];
                    si += y[kx].x*S9[m] + y[kx].y*C9[m];
                }
                T1[(r*5 + ky)*64 + lane] = make_float2(sr, si);
            }
        }
    }
    __syncthreads();
    if (j < 9) {   // phase 2: IFFT st2 (doubled-real) + PR + FFT st1, row r=j
        int r = j;
        float2 t1[5];
        #pragma unroll
        for (int ky = 0; ky < 5; ++ky) t1[ky] = T1[(r*5 + ky)*64 + lane];
        float tn[9];
        #pragma unroll
        for (int xc = 0; xc < 9; ++xc) {
            float yr = t1[0].x;
            #pragma unroll
            for (int ky = 1; ky < 5; ++ky) {
                const int m = (xc*ky) % 9;
                yr += 2.f*(t1[ky].x*C9[m] - t1[ky].y*S9[m]);
            }
            yr *= (1.f/81.f);
            int gi = (r*9 + xc)*NIMG + gimg;
            float u12v = u12T[gi];
            float un = 2.f*yr - u12v;
            bool interior = (r >= 1 && r <= 7 && xc >= 1 && xc <= 7);
            float zn = interior ? fmaxf(un, 0.f) : 0.f;
            float u12n = 2.f*zn - un;
            u12T[gi] = u12n;
            tn[xc] = last ? zn : (u12n + biasT[gi]);
        }
        #pragma unroll
        for (int ky = 0; ky < 5; ++ky) {
            float sr = 0.f, si = 0.f;
            #pragma unroll
            for (int xx = 0; xx < 9; ++xx) {
                const int m = (ky*xx) % 9;
                sr += tn[xx]*C9[m];
                si -= tn[xx]*S9[m];
            }
            T1[(r*5 + ky)*64 + lane] = make_float2(sr, si);
        }
    }
    __syncthreads();
    {   // phase 3: FFT st2; column ky = j>>1, kx split by j&1
        int ky = j >> 1;
        float2 s[9];
        #pragma unroll
        for (int rr = 0; rr < 9; ++rr) s[rr] = T1[(rr*5 + ky)*64 + lane];
        if ((j & 1) == 0) {
            #pragma unroll
            for (int kx = 0; kx < 5; ++kx) {
                float fr = 0.f, fi = 0.f;
                #pragma unroll
                for (int rr = 0; rr < 9; ++rr) {
                    const int m = (kx*rr) % 9;
                    fr += s[rr].x*C9[m] + s[rr].y*S9[m];
                    fi += s[rr].y*C9[m] - s[rr].x*S9[m];
                }
                Tf[(kx*9 + ky)*NIMG + gimg] = make_float2(fr, fi);
            }
        } else if (ky > 0) {
            #pragma unroll
            for (int kx = 5; kx < 9; ++kx) {
                float fr = 0.f, fi = 0.f;
                #pragma unroll
                for (int rr = 0; rr < 9; ++rr) {
                    const int m = (kx*rr) % 9;
                    fr += s[rr].x*C9[m] + s[rr].y*S9[m];
                    fi += s[rr].y*C9[m] - s[rr].x*S9[m];
                }
                Tf[(kx*9 + ky)*NIMG + gimg] = make_float2(fr, fi);
            }
        }
    }
}

// ---------------- final: IFFT(W z) -> relu(+bias) -> crop, 320 thr ---------
__global__ __launch_bounds__(320) void k_crop(const float2* __restrict__ Yf,
                                              const float* __restrict__ biasT,
                                              float* __restrict__ zc) {
    __shared__ float2 T1[9*5*64];
    int lane = threadIdx.x & 63, j = threadIdx.x >> 6;
    int gimg = blockIdx.x*64 + lane;
    {   // mirror-load + IFFT st1, column ky = j
        int ky = j;
        float2 y[9];
        #pragma unroll
        for (int kx = 0; kx < 9; ++kx) {
            int fc; bool cj;
            if (ky == 0 && kx >= 5) { fc = (9 - kx)*9; cj = true; }
            else                    { fc = kx*9 + ky;  cj = false; }
            float2 a = Yf[fc*NIMG + gimg];
            y[kx] = make_float2(a.x, cj ? -a.y : a.y);
        }
        #pragma unroll
        for (int r = 0; r < 9; ++r) {
            float sr = 0.f, si = 0.f;
            #pragma unroll
            for (int kx = 0; kx < 9; ++kx) {
                const int m = (r*kx) % 9;
                sr += y[kx].x*C9[m] - y[kx].y*S9[m];
                si += y[kx].x*S9[m] + y[kx].y*C9[m];
            }
            T1[(r*5 + ky)*64 + lane] = make_float2(sr, si);
        }
    }
    __syncthreads();
    for (int r = 1 + j; r <= 7; r += 5) {
        float2 t1[5];
        #pragma unroll
        for (int ky = 0; ky < 5; ++ky) t1[ky] = T1[(r*5 + ky)*64 + lane];
        float* zr = zc + (gimg >> 6)*3136 + (gimg & 63)*49 + (r-1)*7;
        #pragma unroll
        for (int xc = 1; xc < 8; ++xc) {
            float yr = t1[0].x;
            #pragma unroll
            for (int ky = 1; ky < 5; ++ky) {
                const int m = (xc*ky) % 9;
                yr += 2.f*(t1[ky].x*C9[m] - t1[ky].y*S9[m]);
            }
            yr *= (1.f/81.f);
            zr[xc-1] = fmaxf(yr + biasT[(r*9 + xc)*NIMG + gimg], 0.f);
        }
    }
}

// ---------------- fc1: (256x3136)x(512x3136)^T + b, relu -------------------
// float4-vectorized inner loop over kk: 2 ds_read_b128 per 4 FMA.
__global__ __launch_bounds__(256) void k_fc1(const float* __restrict__ A,
                                             const float* __restrict__ W,
                                             const float* __restrict__ bb,
                                             float* __restrict__ H) {
    int bt = blockIdx.x >> 5, ot = blockIdx.x & 31;
    int b0 = bt*16, o0 = ot*16;
    __shared__ float At[16][68], Bt[16][68];   // 68: 16B-aligned rows, 2-way ok
    int tid = threadIdx.x;
    int row = tid >> 4, col4 = (tid & 15) * 4; // one float4 per thread per tile
    int tb = tid >> 4, to = tid & 15;
    float acc = 0.f;
    for (int k0 = 0; k0 < 3136; k0 += 64) {
        *(float4*)&At[row][col4] = *(const float4*)&A[(b0+row)*3136 + k0 + col4];
        *(float4*)&Bt[row][col4] = *(const float4*)&W[(o0+row)*3136 + k0 + col4];
        __syncthreads();
        #pragma unroll
        for (int kk = 0; kk < 64; kk += 4) {
            float4 av = *(const float4*)&At[tb][kk];
            float4 bv = *(const float4*)&Bt[to][kk];
            acc += av.x*bv.x + av.y*bv.y + av.z*bv.z + av.w*bv.w;
        }
        __syncthreads();
    }
    H[(b0+tb)*512 + o0+to] = fmaxf(acc + bb[o0+to], 0.f);
}

// ---------------- fc2: (256x512)x(18x512)^T + b ----------------------------
__global__ __launch_bounds__(256) void k_fc2(const float* __restrict__ H,
                                             const float* __restrict__ W,
                                             const float* __restrict__ bb,
                                             float* __restrict__ out) {
    int idx = blockIdx.x*256 + threadIdx.x;
    if (idx >= 4608) return;
    int b = idx/18, o = idx%18;
    const float* h = H + b*512;
    const float* w = W + o*512;
    float acc = 0.f;
    for (int k = 0; k < 512; k++) acc += h[k]*w[k];
    out[idx] = acc + bb[o];
}

// ---------------------------------------------------------------------------
extern "C" void kernel_launch(void* const* d_in, const int* in_sizes, int n_in,
                              void* d_out, int out_size, void* d_ws, size_t ws_size,
                              hipStream_t stream) {
    (void)in_sizes; (void)n_in; (void)out_size; (void)ws_size;
    const float* x   = (const float*)d_in[0];
    const float* c1w = (const float*)d_in[1];
    const float* c1b = (const float*)d_in[2];
    const float* c2w = (const float*)d_in[3];
    const float* c2b = (const float*)d_in[4];
    const float* Uw  = (const float*)d_in[5];
    const float* Ub  = (const float*)d_in[6];
    const float* Aw  = (const float*)d_in[7];
    const float* gp  = (const float*)d_in[8];
    const float* f1w = (const float*)d_in[9];
    const float* f1b = (const float*)d_in[10];
    const float* f2w = (const float*)d_in[11];
    const float* f2b = (const float*)d_in[12];

    float* ws = (float*)d_ws;
    float*  h1    = ws + 0;                      // 3,276,800 f
    float2* Tf    = (float2*)(ws + 0);           // alias h1 (dead after conv2)
    float*  biasT = ws + 3276800;                // 1,327,104 f  [p][img]
    float*  u12T  = ws + 4603904;                // 1,327,104 f  [p][img]
    float2* Yf    = (float2*)(ws + 5931008);     // 1,327,104 c2
    float2* Af    = (float2*)(ws + 8585216);     // 331,776 c2
    float2* Minv  = (float2*)(ws + 9248768);     // 331,776 c2
    float2* WmT   = (float2*)(ws + 9912320);     // 331,776 c2
    float*  zc    = ws + 10575872;               // 802,816 f
    float*  hfc   = ws + 11378688;               // 131,072 f
    float*  sc    = ws + 11509760;               // 2 f
    float*  h2    = ws + 11509764;               // 1,327,104 f

    hipMemsetAsync(u12T, 0, (size_t)1327104*sizeof(float), stream);

    k_norm <<<1,     256, 0, stream>>>(Aw, sc);
    k_conv1<<<512,   512, 0, stream>>>(x, c1w, c1b, h1);
    k_conv2<<<1024,  512, 0, stream>>>(h1, c2w, c2b, h2);
    k_bias <<<1024,  512, 0, stream>>>(h2, Uw, Ub, biasT);
    k_af   <<<NCAN,  256, 0, stream>>>(Aw, sc, Af);
    k_mw   <<<NCAN*4,256, 0, stream>>>(Af, gp, Minv, WmT);
    k_inv  <<<NCAN,  512, 0, stream>>>(Minv);

    // iteration 0 forward: u12 = 0, so T = FFT(bias)
    k_fft<<<256, 320, 0, stream>>>(biasT, Tf);
    for (int it = 0; it < MAXIT; it++) {
        k_mv  <<<NCAN*16, 256, 0, stream>>>(Tf, Yf, Minv);
        k_fuse<<<256,     640, 0, stream>>>(Yf, u12T, biasT, Tf, it == MAXIT-1);
    }
    // final pass: brelu(W z + bias) -> crop  (Tf already = FFT(z))
    k_mv  <<<NCAN*16, 256, 0, stream>>>(Tf, Yf, WmT);
    k_crop<<<256,     320, 0, stream>>>(Yf, biasT, zc);

    k_fc1<<<512, 256, 0, stream>>>(zc, f1w, f1b, hfc);
    k_fc2<<<18,  256, 0, stream>>>(hfc, f2w, f2b, (float*)d_out);
}